// Round 11
// baseline (115.763 us; speedup 1.0000x reference)
//
#include <hip/hip_runtime.h>
#include <cmath>

#define T_TOKENS 16384
#define DIM 2048
#define HH 64
#define NG 4
#define EPG 16
#define NE 64
#define NJ 132
#define NT 9            // n-tiles of 16 (144 padded)
#define BM 64           // tokens per block
#define BK 128          // k per iteration (4 ksteps of 32)
#define NITER (DIM / BK)    // 16
#define TAU 0.02f
#define KEPS 1.5e-3f

#define XBUF_B 32768    // 64 tokens * 512 B
#define WBUF_B 36864    // 36 cells * 1 KB
#define XS_OFF 0        // xs bufs at [0, 65536)
#define WS_OFF 65536    // ws bufs at [65536, 139264)

typedef __attribute__((ext_vector_type(8))) short bf16x8;
typedef __attribute__((ext_vector_type(4))) float f32x4;

// ws float-offsets
#define WF_FLOATS (64 * NT * 64 * 4)    // fragment-linear bf16 weights, 64 ksteps
#define SUM_OFF WF_FLOATS               // 128 floats: usage, rp
#define CNT_OFF (SUM_OFF + 128)
#define LIST_OFF (CNT_OFF + 4)          // int4 entries (16B aligned)

static __device__ inline unsigned bf16rne(float x) {
    unsigned u = __float_as_uint(x);
    return (u + 0x7FFFu + ((u >> 16) & 1u)) >> 16;
}

#define GLOAD_LDS(gsrc, ldst) \
    __builtin_amdgcn_global_load_lds( \
        (const __attribute__((address_space(1))) void*)(gsrc), \
        (__attribute__((address_space(3))) void*)(ldst), 16, 0, 0)

// Build fragment-linear bf16 weight buffer: [kstep 64][ntile 9][lane 64][16B]
__global__ void moe_prep(const float* __restrict__ Wg, const float* __restrict__ We,
                         const float* __restrict__ W1, float* __restrict__ ws,
                         float* __restrict__ sums, int* __restrict__ cnt) {
    int bid = blockIdx.x;                 // 576
    int kstep = bid / NT, nt = bid % NT;
    int lane = threadIdx.x;               // 64
    if (bid == 0) {
        sums[lane] = 0.f; sums[64 + lane] = 0.f;
        if (lane == 0) *cnt = 0;
    }
    int row = nt * 16 + (lane & 15);
    int k0 = kstep * 32 + (lane >> 4) * 8;
    const float* src = nullptr;
    if (row < HH)            src = W1 + (size_t)row * DIM;
    else if (row < HH + NG)  src = Wg + (size_t)(row - HH) * DIM;
    else if (row < NJ)       src = We + (size_t)(row - HH - NG) * DIM;
    unsigned r0 = 0, r1 = 0, r2 = 0, r3 = 0;
    if (src) {
        r0 = bf16rne(src[k0 + 0]) | (bf16rne(src[k0 + 1]) << 16);
        r1 = bf16rne(src[k0 + 2]) | (bf16rne(src[k0 + 3]) << 16);
        r2 = bf16rne(src[k0 + 4]) | (bf16rne(src[k0 + 5]) << 16);
        r3 = bf16rne(src[k0 + 6]) | (bf16rne(src[k0 + 7]) << 16);
    }
    ((uint4*)ws)[(size_t)(kstep * NT + nt) * 64 + lane] = make_uint4(r0, r1, r2, r3);
}

// Fused GEMM + epilogue: 256 blocks x 512 threads (8 waves), 64 tokens/block, BK=128.
// All staging via global_load_lds DMA; double-buffered; stage issued right after the
// barrier so DMAs land during the long compute phase.
// Wave roles: mq = wave&3 (16 tokens), nh = wave>>2: tiles {nh+2i}, i=0..(nh?3:4).
__global__ __launch_bounds__(512, 1) void moe_fused(
    const float* __restrict__ x, const float* __restrict__ wfrag,
    const float* __restrict__ b1, const float* __restrict__ W2,
    const float* __restrict__ b2, const int* __restrict__ minE,
    const int* __restrict__ maxE, float* __restrict__ out,
    float* __restrict__ sums, int* __restrict__ cnt, int4* __restrict__ list) {
    __shared__ __align__(16) char smem[XBUF_B * 2 + WBUF_B * 2];   // 136 KB; slog overlays after loop
    __shared__ float rp_s[BM * 17];
    __shared__ float sc_n1[BM], sc_n2[BM], sc_u2[BM];
    __shared__ int   sc_e1[BM], sc_e2[BM];
    __shared__ float s_usage[NE], s_rp[NE];

    const int tid = threadIdx.x;          // 0..511
    const int wave = tid >> 6, lane = tid & 63;
    const int l15 = lane & 15, lq = lane >> 4;
    const int T0 = blockIdx.x * BM;

    if (tid < NE) { s_usage[tid] = 0.f; s_rp[tid] = 0.f; }

    // ---- x stage role: 4 instrs/wave; instr j: token xtok = wave*8 + 2j + (lane>>5),
    //      stored unit su = lane&31, global unit gu = su ^ (xtok&7) (pre-swizzled src).
    const int xtok0 = wave * 8 + (lane >> 5);
    const int su = lane & 31;
    const uint4* wg = (const uint4*)wfrag;

    // ---- compute role ----
    const int mq = wave & 3, nh = wave >> 2;
    const int ntiles = nh == 0 ? 5 : 4;
    const int ctok = mq * 16 + l15;
    const int csw = ctok & 7;

    f32x4 acc[5];
    #pragma unroll
    for (int i = 0; i < 5; ++i) acc[i] = (f32x4){0.f, 0.f, 0.f, 0.f};

    auto stage = [&](int it) {
        char* xb = smem + XS_OFF + (it & 1) * XBUF_B;
        char* wb = smem + WS_OFF + (it & 1) * WBUF_B;
        // x: 4 instrs, tokens wave*8 .. wave*8+7
        #pragma unroll
        for (int j = 0; j < 4; ++j) {
            const int tok = xtok0 + 2 * j;
            const float* gsrc = x + (size_t)(T0 + tok) * DIM + it * BK + ((su ^ (tok & 7)) << 2);
            GLOAD_LDS(gsrc, xb + tok * 512 + su * 16);
        }
        // w: cells c = wave + 8j (j=0..3) and +32 for waves 0-3; slab contiguous
        const uint4* wslab = wg + (size_t)it * (36 * 64);
        #pragma unroll
        for (int j = 0; j < 4; ++j) {
            const int c = wave + 8 * j;
            GLOAD_LDS(wslab + c * 64 + lane, wb + c * 1024 + lane * 16);
        }
        if (wave < 4) {
            const int c = wave + 32;
            GLOAD_LDS(wslab + c * 64 + lane, wb + c * 1024 + lane * 16);
        }
    };

    stage(0);
    for (int it = 0; it < NITER; ++it) {
        __syncthreads();                       // drains stage(it); all waves done reading buf (it-1)&1
        if (it + 1 < NITER) stage(it + 1);     // DMAs land during this iter's compute
        const char* xb = smem + XS_OFF + (it & 1) * XBUF_B;
        const char* wb = smem + WS_OFF + (it & 1) * WBUF_B;
        #pragma unroll
        for (int ks = 0; ks < 4; ++ks) {
            const int u0 = (ks * 8 + lq * 2) ^ csw;
            const int u1 = (ks * 8 + lq * 2 + 1) ^ csw;
            uint4 xlo = *(const uint4*)(xb + ctok * 512 + u0 * 16);
            uint4 xhi = *(const uint4*)(xb + ctok * 512 + u1 * 16);
            union { unsigned u[4]; bf16x8 v; } af;
            af.u[0] = (xlo.x >> 16) | (xlo.y & 0xFFFF0000u);
            af.u[1] = (xlo.z >> 16) | (xlo.w & 0xFFFF0000u);
            af.u[2] = (xhi.x >> 16) | (xhi.y & 0xFFFF0000u);
            af.u[3] = (xhi.z >> 16) | (xhi.w & 0xFFFF0000u);
            #pragma unroll
            for (int i = 0; i < 5; ++i) {
                if (i < 4 || nh == 0) {
                    const int nt = nh + 2 * i;
                    bf16x8 bv = *(const bf16x8*)(wb + (ks * 9 + nt) * 1024 + lane * 16);
                    acc[i] = __builtin_amdgcn_mfma_f32_16x16x32_bf16(af.v, bv, acc[i], 0, 0, 0);
                }
            }
        }
    }
    __syncthreads();   // all reads of staging bufs done -> safe to overlay slog

    // dump accumulators: token row = mq*16 + lq*4 + r, col = nt*16 + l15
    float* slog = (float*)smem;            // [64][145] = 37.1 KB
    #pragma unroll
    for (int i = 0; i < 5; ++i) {
        if (i < 4 || nh == 0) {
            const int nt = nh + 2 * i;
            #pragma unroll
            for (int r = 0; r < 4; ++r)
                slog[(mq * 16 + lq * 4 + r) * 145 + nt * 16 + l15] = acc[i][r];
        }
    }
    __syncthreads();

    // parallel epilogue: 16-lane group per token, two halves of 32 tokens
    for (int half = 0; half < 2; ++half) {
        const int t = (tid >> 4) + half * 32;
        const int q = tid & 15;
        const int tok = T0 + t;
        const float* o = slog + t * 145;

        float4 b1v = ((const float4*)b1)[q];
        float4 w2v = ((const float4*)W2)[q];
        float part;
        {
            float h0 = o[q * 4 + 0] + b1v.x; h0 = h0 > 0.f ? h0 : 0.f;
            float h1 = o[q * 4 + 1] + b1v.y; h1 = h1 > 0.f ? h1 : 0.f;
            float h2 = o[q * 4 + 2] + b1v.z; h2 = h2 > 0.f ? h2 : 0.f;
            float h3 = o[q * 4 + 3] + b1v.w; h3 = h3 > 0.f ? h3 : 0.f;
            part = h0 * w2v.x + h1 * w2v.y + h2 * w2v.z + h3 * w2v.w;
        }
        #pragma unroll
        for (int off = 8; off; off >>= 1) part += __shfl_xor(part, off, 16);
        float z = b2[0] + part;
        float c = 1.f / (1.f + expf(-z));
        int mx = maxE[0], mn = minE[0];
        float y = c * (float)mx;
        int k = (int)y; k = k < mn ? mn : (k > mx ? mx : k);
        int kl = (int)(y - KEPS); kl = kl < mn ? mn : (kl > mx ? mx : kl);
        int kh = (int)(y + KEPS); kh = kh < mn ? mn : (kh > mx ? mx : kh);
        bool flagK = (kl != kh);
        float u2 = (k >= 2) ? 1.f : 0.f;

        float gl0 = o[HH + 0], gl1 = o[HH + 1], gl2 = o[HH + 2], gl3 = o[HH + 3];
        float gm = gl0; int gi = 0;
        if (gl1 > gm) { gm = gl1; gi = 1; }
        if (gl2 > gm) { gm = gl2; gi = 2; }
        if (gl3 > gm) { gm = gl3; gi = 3; }
        float g2 = -INFINITY;
        if (gi != 0 && gl0 > g2) g2 = gl0;
        if (gi != 1 && gl1 > g2) g2 = gl1;
        if (gi != 2 && gl2 > g2) g2 = gl2;
        if (gi != 3 && gl3 > g2) g2 = gl3;
        bool flagG = (gm - g2) < TAU;
        float gsum = expf(gl0 - gm) + expf(gl1 - gm) + expf(gl2 - gm) + expf(gl3 - gm);
        float gp = 1.f / gsum;

        float el = o[HH + NG + gi * EPG + q];
        float v1v = el; int i1 = q;
        #pragma unroll
        for (int off = 8; off; off >>= 1) {
            float ov = __shfl_xor(v1v, off, 16);
            int   oi = __shfl_xor(i1, off, 16);
            if (ov > v1v || (ov == v1v && oi < i1)) { v1v = ov; i1 = oi; }
        }
        float v2v = (q == i1) ? -INFINITY : el; int i2 = q;
        #pragma unroll
        for (int off = 8; off; off >>= 1) {
            float ov = __shfl_xor(v2v, off, 16);
            int   oi = __shfl_xor(i2, off, 16);
            if (ov > v2v || (ov == v2v && oi < i2)) { v2v = ov; i2 = oi; }
        }
        float e3v = (q == i1 || q == i2) ? -INFINITY : el;
        #pragma unroll
        for (int off = 8; off; off >>= 1)
            e3v = fmaxf(e3v, __shfl_xor(e3v, off, 16));
        bool flagE = ((v1v - v2v) < TAU) || (u2 > 0.f && (v2v - e3v) < TAU);

        float ep = expf(el - v1v);
        float es = ep;
        #pragma unroll
        for (int off = 8; off; off >>= 1) es += __shfl_xor(es, off, 16);
        float inv = 1.f / es;
        rp_s[t * 17 + q] = gp * ep * inv;

        if (q == 0) {
            float v1p = inv;
            float v2p = expf(v2v - v1v) * inv;
            float denom = v1p + v2p * u2;
            sc_n1[t] = v1p / denom; sc_n2[t] = v2p * u2 / denom; sc_u2[t] = u2;
            sc_e1[t] = gi * EPG + i1; sc_e2[t] = gi * EPG + i2;
            if (flagK || flagG || flagE) {
                int p = atomicAdd(cnt, 1);
                int fl = (flagG ? 1 : 0) | (flagE ? 2 : 0) | (flagK ? 4 : 0);
                list[p] = make_int4(tok, fl, (int)u2, 0);
            }
        }
    }
    __syncthreads();

    float* outD = out;
    float* outC = out + (size_t)T_TOKENS * NE;
    float* outR = out + (size_t)2 * T_TOKENS * NE;
    for (int idx = tid; idx < BM * NE; idx += 512) {
        int t = idx >> 6, e = idx & 63;
        int e1i = sc_e1[t], e2i = sc_e2[t];
        int gi = e1i >> 4;
        float disp = (e == e1i ? 1.f : 0.f) + (e == e2i ? sc_u2[t] : 0.f);
        float comb = (e == e1i ? sc_n1[t] : 0.f) + (e == e2i ? sc_n2[t] : 0.f);
        float rpv  = ((e >> 4) == gi) ? rp_s[t * 17 + (e & 15)] : 0.f;
        size_t ob = (size_t)(T0 + t) * NE + e;
        outD[ob] = disp; outC[ob] = comb; outR[ob] = rpv;
        atomicAdd(&s_usage[e], disp);
        atomicAdd(&s_rp[e], rpv);
    }
    __syncthreads();
    if (tid < NE) {
        atomicAdd(&sums[tid], s_usage[tid]);
        atomicAdd(&sums[NE + tid], s_rp[tid]);
    }
}

// parallel fixup: one block (4 waves) per flagged token
__global__ __launch_bounds__(256, 4) void moe_fix(
    const float* __restrict__ x, const float* __restrict__ Wg,
    const float* __restrict__ We, const float* __restrict__ W1,
    const float* __restrict__ b1, const float* __restrict__ W2,
    const float* __restrict__ b2, const int* __restrict__ minE,
    const int* __restrict__ maxE, float* __restrict__ out,
    float* __restrict__ sums, const int* __restrict__ cnt,
    const int4* __restrict__ list) {
    __shared__ float gl_s[NG];
    __shared__ float h_s[HH];
    __shared__ float el_s[EPG];
    __shared__ float rp_row[EPG];
    __shared__ int   s_gi;
    __shared__ float s_u2, s_gp;
    __shared__ int   s_e1, s_e2;
    __shared__ float s_n1, s_n2;

    const int tid = threadIdx.x;
    const int wave = tid >> 6, lane = tid & 63;
    const int n = *cnt;

    for (int i = blockIdx.x; i < n; i += gridDim.x) {
        const int4 ent = list[i];
        const int tok = ent.x, fl = ent.y;
        const float u2_in = (float)ent.z;

        const float* xrow = x + (size_t)tok * DIM;
        float xr[32];
        #pragma unroll
        for (int m = 0; m < 32; ++m) xr[m] = xrow[lane + m * 64];

        auto dotf = [&](const float* w) -> float {
            float s = 0.f;
            #pragma unroll
            for (int m = 0; m < 32; ++m) s = fmaf(xr[m], w[lane + m * 64], s);
            #pragma unroll
            for (int off = 32; off; off >>= 1) s += __shfl_xor(s, off, 64);
            return s;
        };

        {
            float g = dotf(Wg + (size_t)wave * DIM);
            if (lane == 0) gl_s[wave] = g;
        }
        if (fl & 4) {
            for (int j = wave; j < HH; j += 4) {
                float hv = dotf(W1 + (size_t)j * DIM);
                if (lane == 0) h_s[j] = hv;
            }
        }
        __syncthreads();

        if (tid == 0) {
            float gm = -INFINITY; int gi = 0;
            #pragma unroll
            for (int g = 0; g < NG; ++g)
                if (gl_s[g] > gm) { gm = gl_s[g]; gi = g; }
            float gsum = 0.f;
            #pragma unroll
            for (int g = 0; g < NG; ++g) gsum += expf(gl_s[g] - gm);
            s_gp = 1.f / gsum;
            s_gi = gi;
            float u2 = u2_in;
            if (fl & 4) {
                float z = b2[0];
                for (int j = 0; j < HH; ++j) {
                    float h = h_s[j] + b1[j];
                    z = fmaf(W2[j], h > 0.f ? h : 0.f, z);
                }
                float c = 1.f / (1.f + expf(-z));
                int mx = maxE[0], mn = minE[0];
                int k = (int)(c * (float)mx);
                k = k < mn ? mn : (k > mx ? mx : k);
                u2 = (k >= 2) ? 1.f : 0.f;
            }
            s_u2 = u2;
        }
        __syncthreads();

        const int gi = s_gi;
        for (int j = wave; j < EPG; j += 4) {
            float e = dotf(We + (size_t)(gi * EPG + j) * DIM);
            if (lane == 0) el_s[j] = e;
        }
        __syncthreads();

        if (tid == 0) {
            float e1 = -INFINITY, e2v = -INFINITY; int i1 = 0, i2 = 0;
            #pragma unroll
            for (int j = 0; j < EPG; ++j) {
                float v = el_s[j];
                if (v > e1)       { e2v = e1; i2 = i1; e1 = v; i1 = j; }
                else if (v > e2v) { e2v = v; i2 = j; }
            }
            float es = 0.f;
            #pragma unroll
            for (int j = 0; j < EPG; ++j) {
                float e = expf(el_s[j] - e1);
                rp_row[j] = e;
                es += e;
            }
            float inv = 1.f / es;
            float gp = s_gp;
            #pragma unroll
            for (int j = 0; j < EPG; ++j) rp_row[j] *= inv * gp;
            float v1 = expf(el_s[i1] - e1) * inv;
            float v2 = expf(el_s[i2] - e1) * inv;
            float u2 = s_u2;
            float denom = v1 + v2 * u2;
            s_n1 = v1 / denom; s_n2 = v2 * u2 / denom;
            s_e1 = gi * EPG + i1; s_e2 = gi * EPG + i2;
        }
        __syncthreads();

        if (tid < NE) {
            const int e = tid;
            float u2 = s_u2;
            float newD = (e == s_e1 ? 1.f : 0.f) + (e == s_e2 ? u2 : 0.f);
            float newC = (e == s_e1 ? s_n1 : 0.f) + (e == s_e2 ? s_n2 : 0.f);
            float newR = ((e >> 4) == gi) ? rp_row[e & 15] : 0.f;
            size_t ob = (size_t)tok * NE + e;
            float oldD = out[ob];
            float oldR = out[(size_t)2 * T_TOKENS * NE + ob];
            out[ob] = newD;
            out[(size_t)T_TOKENS * NE + ob] = newC;
            out[(size_t)2 * T_TOKENS * NE + ob] = newR;
            float dD = newD - oldD, dR = newR - oldR;
            if (dD != 0.f) atomicAdd(&sums[e], dD);
            if (dR != 0.f) atomicAdd(&sums[NE + e], dR);
        }
        __syncthreads();
    }
}

__global__ void moe_finalize(const float* __restrict__ sums, float* __restrict__ out) {
    int l = threadIdx.x;
    float v = sums[l] * sums[NE + l];
    #pragma unroll
    for (int off = 32; off; off >>= 1) v += __shfl_down(v, off, 64);
    if (l == 0) {
        float N = (float)T_TOKENS;
        out[(size_t)3 * T_TOKENS * NE] = v * (float)NE / (N * N);
    }
}

extern "C" void kernel_launch(void* const* d_in, const int* in_sizes, int n_in,
                              void* d_out, int out_size, void* d_ws, size_t ws_size,
                              hipStream_t stream) {
    const float* x  = (const float*)d_in[0];
    const float* Wg = (const float*)d_in[1];
    const float* We = (const float*)d_in[2];
    const float* W1 = (const float*)d_in[3];
    const float* b1 = (const float*)d_in[4];
    const float* W2 = (const float*)d_in[5];
    const float* b2 = (const float*)d_in[6];
    const int* minE = (const int*)d_in[7];
    const int* maxE = (const int*)d_in[8];
    float* out = (float*)d_out;
    float* ws  = (float*)d_ws;

    float* wfrag = ws;
    float* sums  = ws + SUM_OFF;
    int*   cnt   = (int*)(ws + CNT_OFF);
    int4*  list  = (int4*)(ws + LIST_OFF);

    moe_prep<<<64 * NT, 64, 0, stream>>>(Wg, We, W1, wfrag, sums, cnt);
    moe_fused<<<T_TOKENS / BM, 512, 0, stream>>>(x, wfrag, b1, W2, b2, minE, maxE,
                                                 out, sums, cnt, list);
    moe_fix<<<2048, 256, 0, stream>>>(x, Wg, We, W1, b1, W2, b2, minE, maxE,
                                      out, sums, cnt, list);
    moe_finalize<<<1, 64, 0, stream>>>(sums, out);
}